// Round 1
// baseline (82.336 us; speedup 1.0000x reference)
//
#include <hip/hip_runtime.h>
#include <hip/hip_bf16.h>

// NT-Xent (SimCLR) loss, MI355X gfx950.
// loss = (1/N) * sum_i [ ln(S_i - exp2(C1*d_ii)) - (2/C1)*dp_i ]
//   where d = zhat.zhat^T (unit rows), C1 = 2*log2(e),
//   S_i = sum_j exp2(C1*d_ij), dp_i = C1 * d_{i, i^B}.
// zb stores sqrt(C1)*zhat in bf16, pre-swizzled into MFMA fragment order:
// 16B chunk for (tile=row>>4, c, lane=quad*16+t) at uint4 index
//   (tile*4+c)*64 + lane, covering row=tile*16+t, k in [c*32+quad*8, +8).
// R6: exploit sim symmetry -- compute only the upper triangle of the 64x64
// grid of 128x128 tiles (2080 tiles). Each off-diag tile contributes BOTH
// row-sums (slot bj) and col-sums (slot bi, via quad-butterfly + 1KB LDS
// cross-wave reduce) -> MFMA + exp2 work x0.51. 64 diag tiles merged
// pairwise into 32 two-pass blocks (scheduled first: 2x duration) so the
// grid is exactly 2048 blocks = 2 full dispatch rounds at 4 blocks/CU.
// Blocks are 128 thr / 2 waves; each wave owns 64 rows (rt=4) so B-frag
// reuse stays 4 -> LDS ds_read_b128 count halves along with MFMA.
// R5 lesson kept: stage B-span via global_load_lds width=16 (swizzled
// layout is exactly DMA order), barrier-free compute loop.
// R4 lesson kept: minimal live registers, no ping-pong.

#define NN 8192
#define BHALF 4096
#define DIMK 128

typedef __bf16 bf16x8 __attribute__((ext_vector_type(8)));
typedef float f32x4 __attribute__((ext_vector_type(4)));

#define C1F 2.8853900817779268f   // 2*log2(e)
#define SCALEF 1.6986436f         // sqrt(C1)

// ---------------- Kernel A: normalize, scale by sqrt(C1), swizzle ----------
__global__ __launch_bounds__(256) void nt_normalize(
    const float* __restrict__ zi, const float* __restrict__ zj,
    unsigned int* __restrict__ zb_packed, float* __restrict__ out) {
  if (blockIdx.x == 0 && threadIdx.x == 0) out[0] = 0.0f;  // runs before finalize
  int row = blockIdx.x * 4 + (threadIdx.x >> 6);
  int lane = threadIdx.x & 63;
  const float* src = (row < BHALF) ? (zi + (size_t)row * DIMK)
                                   : (zj + (size_t)(row - BHALF) * DIMK);
  float2 v = ((const float2*)src)[lane];
  float ss = v.x * v.x + v.y * v.y;
#pragma unroll
  for (int off = 32; off >= 1; off >>= 1) ss += __shfl_xor(ss, off, 64);
  float rn = rsqrtf(ss) * SCALEF;
  __hip_bfloat16 h0 = __float2bfloat16(v.x * rn);
  __hip_bfloat16 h1 = __float2bfloat16(v.y * rn);
  unsigned int packed = ((unsigned int)(*(unsigned short*)&h1) << 16) |
                        (*(unsigned short*)&h0);
  int tile = row >> 4, t = row & 15;
  int cq = lane >> 2;               // chunk index 0..15 (= c*4 + quad)
  int c = cq >> 2, quad = cq & 3;
  size_t widx = ((size_t)((tile * 4 + c) * 64 + quad * 16 + t)) * 4 + (lane & 3);
  zb_packed[widx] = packed;
}

// ---------------- Kernel B: triangular streaming sim + exp2 ----------------
// Grid = 2048 blocks x 128 threads (2 waves). Block u<32: diag pair
// (u,u) then (u+32,u+32), two passes. Block u>=32: off-diag tile (bi,bj),
// bi<bj over 64 strips of 128 rows. C/D: col=lane&15, row=quad*4+reg.
__global__ __launch_bounds__(128, 2) void nt_sim(
    const uint4* __restrict__ zbv, float* __restrict__ part) {
  __shared__ uint4 ldsb[2048];      // 32 KiB: B-span (128 cols of strip bj)
  __shared__ float colbuf[2][128];  // 1 KiB: cross-wave col partial sums

  const int lane = threadIdx.x & 63;
  const int wave = threadIdx.x >> 6;
  const int quad = lane >> 4;
  const int t = lane & 15;

  const int u = blockIdx.x;
  const bool offdiag = (u >= 32);
  int bi, bj;
  if (!offdiag) {
    bi = u; bj = u;
  } else {
    // strict upper triangle over 64 strips: S'(i) = i*(127-i)/2
    int v = u - 32;
    bi = (int)((127.0f - sqrtf(16129.0f - 8.0f * (float)v)) * 0.5f);
    while ((bi + 1) * (127 - (bi + 1)) / 2 <= v) ++bi;
    while (bi * (127 - bi) / 2 > v) --bi;
    bj = bi + 1 + (v - bi * (127 - bi) / 2);
  }
  const int npass = offdiag ? 1 : 2;

  for (int pass = 0; pass < npass; ++pass) {
    if (pass) {
      bi += 32; bj += 32;
      __syncthreads();  // all waves done reading ldsb before re-staging
    }

    // ---- async-stage the 32KB B-span: 32 chunks of 1KB, 16 instrs/wave ----
    {
      const char* gsrc = (const char*)zbv + (size_t)bj * 32768;
#pragma unroll
      for (int k = 0; k < 16; ++k) {
        int chunk = k * 2 + wave;
        __builtin_amdgcn_global_load_lds(
            (const __attribute__((address_space(1))) unsigned int*)(
                gsrc + chunk * 1024 + lane * 16),
            (__attribute__((address_space(3))) unsigned int*)(
                (char*)ldsb + chunk * 1024),
            16, 0, 0);
      }
    }

    // ---- A fragments (4 row-tiles = 64 rows/wave), overlaps with DMA ----
    const int row_tile0 = bi * 8 + wave * 4;
    bf16x8 A[4][4];  // [row-tile][K-chunk]
#pragma unroll
    for (int rt = 0; rt < 4; ++rt)
#pragma unroll
      for (int c = 0; c < 4; ++c)
        A[rt][c] = __builtin_bit_cast(
            bf16x8, zbv[(size_t)((row_tile0 + rt) * 4 + c) * 64 + lane]);

    float sum[4][4];
#pragma unroll
    for (int rt = 0; rt < 4; ++rt)
#pragma unroll
      for (int r = 0; r < 4; ++r) sum[rt][r] = 0.f;

    __syncthreads();  // DMA drain (vmcnt(0)) + join

    // ---- barrier-free compute loop: 8 col-tiles from LDS ----
#pragma unroll 2
    for (int ct = 0; ct < 8; ++ct) {
      f32x4 acc[4];
#pragma unroll
      for (int rt = 0; rt < 4; ++rt) acc[rt] = (f32x4){0.f, 0.f, 0.f, 0.f};
#pragma unroll
      for (int c = 0; c < 4; ++c) {
        bf16x8 bv = __builtin_bit_cast(bf16x8, ldsb[(ct * 4 + c) * 64 + lane]);
#pragma unroll
        for (int rt = 0; rt < 4; ++rt)
          acc[rt] = __builtin_amdgcn_mfma_f32_16x16x32_bf16(A[rt][c], bv,
                                                            acc[rt], 0, 0, 0);
      }
      float cs = 0.f;
#pragma unroll
      for (int rt = 0; rt < 4; ++rt)
#pragma unroll
        for (int r = 0; r < 4; ++r) {
          float e = __builtin_amdgcn_exp2f(acc[rt][r]);
          sum[rt][r] += e;  // row accumulator (over cols)
          cs += e;          // col partial (this lane's 16 rows, col t)
        }
      // reduce col partial over the 4 quads -> wave-total per col
      cs += __shfl_xor(cs, 16, 64);
      cs += __shfl_xor(cs, 32, 64);
      if (quad == 0) colbuf[wave][ct * 16 + t] = cs;
    }

    // ---- row sums: reduce over the 16 col-lanes within each quad ----
#pragma unroll
    for (int off = 8; off >= 1; off >>= 1)
#pragma unroll
      for (int rt = 0; rt < 4; ++rt)
#pragma unroll
        for (int r = 0; r < 4; ++r)
          sum[rt][r] += __shfl_xor(sum[rt][r], off, 16);

    if (t == 0) {
      // slot bj, entries = rows of strip bi
      float* dst = part + (size_t)bj * NN + bi * 128 + wave * 64;
#pragma unroll
      for (int rt = 0; rt < 4; ++rt)
#pragma unroll
        for (int r = 0; r < 4; ++r)
          dst[rt * 16 + quad * 4 + r] = sum[rt][r];
    }

    if (offdiag) {
      __syncthreads();  // colbuf writes from both waves visible
      // slot bi, entries = cols of strip bj (symmetric contribution)
      part[(size_t)bi * NN + bj * 128 + threadIdx.x] =
          colbuf[0][threadIdx.x] + colbuf[1][threadIdx.x];
    }
  }
}

// ---------------- Kernel C: finalize ----------------
__device__ __forceinline__ float bf2f(unsigned short s) {
  unsigned int u = (unsigned int)s << 16;
  return __builtin_bit_cast(float, u);
}

__global__ __launch_bounds__(256) void nt_finalize(
    const uint4* __restrict__ zbv, const float* __restrict__ part,
    float* __restrict__ out) {
  int i = blockIdx.x * 256 + threadIdx.x;
  int tile = i >> 4, t = i & 15;
  int p = i ^ BHALF;
  int tilep = p >> 4;
  float S = 0.f;
#pragma unroll
  for (int k = 0; k < 64; ++k) S += part[(size_t)k * NN + i];
  float dp = 0.f, dd = 0.f;
#pragma unroll
  for (int cq = 0; cq < 16; ++cq) {
    int c = cq >> 2, q = cq & 3;
    uint4 ua = zbv[(size_t)((tile * 4 + c) * 64 + q * 16 + t)];
    uint4 up = zbv[(size_t)((tilep * 4 + c) * 64 + q * 16 + t)];
    const unsigned short* pa = (const unsigned short*)&ua;
    const unsigned short* pp = (const unsigned short*)&up;
#pragma unroll
    for (int k = 0; k < 8; ++k) {
      float a = bf2f(pa[k]), pv = bf2f(pp[k]);
      dd = fmaf(a, a, dd);
      dp = fmaf(a, pv, dp);
    }
  }
  float diag = __builtin_amdgcn_exp2f(dd);        // exp2(C1 * d_ii)
  float v = logf(S - diag) - (2.0f / C1F) * dp;   // lse_i - pos_i
#pragma unroll
  for (int off = 32; off >= 1; off >>= 1) v += __shfl_xor(v, off, 64);
  __shared__ float wsum[4];
  if ((threadIdx.x & 63) == 0) wsum[threadIdx.x >> 6] = v;
  __syncthreads();
  if (threadIdx.x == 0)
    atomicAdd(out, (wsum[0] + wsum[1] + wsum[2] + wsum[3]) * (1.0f / (float)NN));
}

extern "C" void kernel_launch(void* const* d_in, const int* in_sizes, int n_in,
                              void* d_out, int out_size, void* d_ws,
                              size_t ws_size, hipStream_t stream) {
  const float* zi = (const float*)d_in[0];
  const float* zj = (const float*)d_in[1];

  // ws: zb swizzled bf16 (2 MiB) | part[64][8192] (2 MiB)
  unsigned int* zb = (unsigned int*)d_ws;
  float* part = (float*)((char*)d_ws + (2u << 20));

  nt_normalize<<<NN / 4, 256, 0, stream>>>(zi, zj, zb, (float*)d_out);

  // 32 merged diag-pair blocks (2 passes each) first, then 2016 off-diag
  nt_sim<<<2048, 128, 0, stream>>>((const uint4*)zb, part);

  nt_finalize<<<NN / 256, 256, 0, stream>>>((const uint4*)zb, part,
                                            (float*)d_out);
}